// Round 7
// baseline (390.188 us; speedup 1.0000x reference)
//
#include <hip/hip_runtime.h>
#include <hip/hip_bf16.h>

#define B_ 4
#define T_ 2048
#define E_ 1024
#define H_ 16
#define D_ 64
#define M_ (B_*T_)   // 8192 rows

typedef short bf16x8 __attribute__((ext_vector_type(8)));
typedef float f32x4  __attribute__((ext_vector_type(4)));

__device__ __forceinline__ short f2bf(float f) {
    __hip_bfloat16 h = __float2bfloat16(f);
    return *reinterpret_cast<short*>(&h);
}

// round-half-up fp32->bf16 pack of two values into a u32
__device__ __forceinline__ unsigned int pk2(float a, float b) {
    unsigned int ua = __float_as_uint(a), ub = __float_as_uint(b);
    return ((ua + 0x8000u) >> 16) | ((ub + 0x8000u) & 0xffff0000u);
}

__device__ __forceinline__ void async_ld16(const void* g, void* l) {
    __builtin_amdgcn_global_load_lds(
        (const __attribute__((address_space(1))) unsigned int*)g,
        (__attribute__((address_space(3))) unsigned int*)l, 16, 0, 0);
}

// ---------------------------------------------------------------------------
// Prep: fp32 -> bf16 elementwise (x and Wo).
// ---------------------------------------------------------------------------
__global__ void conv_bf16(const float* __restrict__ src, short* __restrict__ dst) {
    const int i = blockIdx.x * 256 + threadIdx.x;
    float4 v = ((const float4*)src)[i];
    short4 o = make_short4(f2bf(v.x), f2bf(v.y), f2bf(v.z), f2bf(v.w));
    ((short4*)dst)[i] = o;
}

// ---------------------------------------------------------------------------
// Prep: bias_pre[b][s] = ((1-mask)*(-3.4e38)) * 1.4427 - 6*1.4427
// (exp2-folded additive bias with static max m=6). mask=1 -> -8.6565.
// ---------------------------------------------------------------------------
__global__ void bias_prep(const float* __restrict__ mask, float* __restrict__ bias) {
    const int i = blockIdx.x * 256 + threadIdx.x;
    float bm = (1.0f - mask[i]) * -3.402823466e38f;   // 0 or -3.4e38
    bias[i] = fmaf(bm, 1.4426950f, -8.6561700f);      // -inf ok (exp2 -> 0)
}

// ---------------------------------------------------------------------------
// Prep: Wq/Wk/Wv [H][E][D] fp32 -> Wt [3*1024 n][1024 e] bf16, n = h*64+d.
// ---------------------------------------------------------------------------
__global__ void wtrans(const float* __restrict__ Wq,
                       const float* __restrict__ Wk,
                       const float* __restrict__ Wv,
                       short* __restrict__ Wt) {
    const int which = blockIdx.z;
    const float* __restrict__ W = (which == 0) ? Wq : (which == 1) ? Wk : Wv;
    const int h  = blockIdx.y;
    const int e0 = blockIdx.x * 64;

    __shared__ float tile[64][65];
    const int tid = threadIdx.x;

#pragma unroll
    for (int r = 0; r < 4; ++r) {
        int lin = tid + r * 256;
        int er = lin >> 4, c4 = (lin & 15) * 4;
        float4 v = *(const float4*)(W + ((size_t)h * E_ + e0 + er) * D_ + c4);
        tile[er][c4 + 0] = v.x; tile[er][c4 + 1] = v.y;
        tile[er][c4 + 2] = v.z; tile[er][c4 + 3] = v.w;
    }
    __syncthreads();
#pragma unroll
    for (int r = 0; r < 4; ++r) {
        int lin = tid + r * 256;
        int dr = lin >> 4, j4 = (lin & 15) * 4;
        short4 o = make_short4(f2bf(tile[j4 + 0][dr]), f2bf(tile[j4 + 1][dr]),
                               f2bf(tile[j4 + 2][dr]), f2bf(tile[j4 + 3][dr]));
        *(short4*)(Wt + ((size_t)which * 1024 + h * 64 + dr) * E_ + e0 + j4) = o;
    }
}

// ---------------------------------------------------------------------------
// MFMA GEMM (m97 structure).
// MODE 0: C -> q/k bf16 [B,H,T,D] scatter; V directly TRANSPOSED [B,H,D,T]
//         (short4 along t: regs i = 4 consecutive t at fixed d).
// MODE 1: C -> fp32 [M][E] + bias.
// ---------------------------------------------------------------------------
template <int MODE>
__global__ __launch_bounds__(256) void mfma_gemm(
        const short* __restrict__ A,
        const short* __restrict__ Bt,
        short* __restrict__ qo, short* __restrict__ ko, short* __restrict__ vo,
        float* __restrict__ Cout, const float* __restrict__ bo) {
    __shared__ __align__(16) short As[128 * 32];
    __shared__ __align__(16) short Bs[128 * 32];

    const int tid  = threadIdx.x;
    const int wave = tid >> 6, lane = tid & 63;
    const int c = lane & 15, quad = lane >> 4;
    const int wm = wave >> 1, wn = wave & 1;
    const int m0 = blockIdx.x * 128;
    const int n0 = blockIdx.y * 128;

    int rowS[2], kgS[2];
#pragma unroll
    for (int r = 0; r < 2; ++r) {
        int p = r * 256 + wave * 64 + lane;
        rowS[r] = p >> 2;
        kgS[r]  = (p & 3) ^ ((rowS[r] >> 1) & 3);
    }

    f32x4 acc[4][4] = {};

    for (int k0 = 0; k0 < 1024; k0 += 32) {
#pragma unroll
        for (int r = 0; r < 2; ++r) {
            async_ld16(A  + (size_t)(m0 + rowS[r]) * 1024 + k0 + kgS[r] * 8,
                       As + (r * 256 + wave * 64) * 8);
            async_ld16(Bt + (size_t)(n0 + rowS[r]) * 1024 + k0 + kgS[r] * 8,
                       Bs + (r * 256 + wave * 64) * 8);
        }
        __syncthreads();

        bf16x8 af[4], bf[4];
#pragma unroll
        for (int mi = 0; mi < 4; ++mi) {
            int row = wm * 64 + mi * 16 + c;
            int pos = row * 4 + (quad ^ ((row >> 1) & 3));
            af[mi] = *(const bf16x8*)(As + pos * 8);
        }
#pragma unroll
        for (int ni = 0; ni < 4; ++ni) {
            int row = wn * 64 + ni * 16 + c;
            int pos = row * 4 + (quad ^ ((row >> 1) & 3));
            bf[ni] = *(const bf16x8*)(Bs + pos * 8);
        }
#pragma unroll
        for (int mi = 0; mi < 4; ++mi)
#pragma unroll
            for (int ni = 0; ni < 4; ++ni)
                acc[mi][ni] = __builtin_amdgcn_mfma_f32_16x16x32_bf16(
                    af[mi], bf[ni], acc[mi][ni], 0, 0, 0);
        __syncthreads();
    }

    if (MODE == 0) {
        const int which = n0 >> 10;
        const int nb = n0 & 1023;
        if (which == 2) {
            // V: store transposed [b,h,d,t], vectorized short4 along t
#pragma unroll
            for (int mi = 0; mi < 4; ++mi) {
                const int m = m0 + wm * 64 + mi * 16 + quad * 4;
                const int b = m >> 11, t = m & 2047;
#pragma unroll
                for (int ni = 0; ni < 4; ++ni) {
                    const int n = nb + wn * 64 + ni * 16 + c;
                    const int h = n >> 6, d = n & 63;
                    short4 s4 = make_short4(f2bf(acc[mi][ni][0]), f2bf(acc[mi][ni][1]),
                                            f2bf(acc[mi][ni][2]), f2bf(acc[mi][ni][3]));
                    *(short4*)(vo + (((size_t)b * H_ + h) * D_ + d) * T_ + t) = s4;
                }
            }
        } else {
            short* __restrict__ outp = (which == 0) ? qo : ko;
#pragma unroll
            for (int mi = 0; mi < 4; ++mi) {
#pragma unroll
                for (int i = 0; i < 4; ++i) {
                    const int m = m0 + wm * 64 + mi * 16 + quad * 4 + i;
                    const int b = m >> 11, t = m & 2047;
#pragma unroll
                    for (int ni = 0; ni < 4; ++ni) {
                        const int n = nb + wn * 64 + ni * 16 + c;
                        const int h = n >> 6, d = n & 63;
                        outp[(((size_t)b * H_ + h) * T_ + t) * D_ + d] =
                            f2bf(acc[mi][ni][i]);
                    }
                }
            }
        }
    } else {
#pragma unroll
        for (int mi = 0; mi < 4; ++mi) {
#pragma unroll
            for (int i = 0; i < 4; ++i) {
                const int m = m0 + wm * 64 + mi * 16 + quad * 4 + i;
#pragma unroll
                for (int ni = 0; ni < 4; ++ni) {
                    const int n = n0 + wn * 64 + ni * 16 + c;
                    Cout[(size_t)m * E_ + n] = acc[mi][ni][i] + bo[n];
                }
            }
        }
    }
}

// ---------------------------------------------------------------------------
// Flash attention v4: low-register waves for real occupancy.
// grid (H, B, 32), block 256 = 2 groups x 2 key-split waves.
// Group g owns 32 q rows: low [32z+16g,+16) (sub 0), high
// [2048-32z-16(g+1),+16) (sub 1). Wave ws in group takes tiles tt%2==ws.
// Static max (m=6, exp2-folded) => partials linear; merge = 1 add round.
// Accums: o[4][2]=32 + lacc[2]=8 regs -> with launch_bounds(256,4) target
// <=128 total => 4 waves/SIMD (2x round 6).
// Diag masks: low at tt==z (qq=16g+c), high at tt==63-z (qq=16(1-g)+c).
// ---------------------------------------------------------------------------
__global__ __launch_bounds__(256, 4) void flash_attn4(
        const short* __restrict__ qg,
        const short* __restrict__ kg,
        const short* __restrict__ vtg,
        const float* __restrict__ biasg,
        short* __restrict__ attn) {
    const int h = blockIdx.x, b = blockIdx.y;
    const int z = blockIdx.z;                      // 0..31
    const int tid  = threadIdx.x;
    const int wave = tid >> 6, lane = tid & 63;
    const int c = lane & 15, quad = lane >> 4;
    const int g  = wave >> 1;                      // group 0,1
    const int ws = wave & 1;                       // key-split parity

    const int ql0 = 32 * z + 16 * g;               // sub 0 rows
    const int qh0 = T_ - 32 * z - 16 * (g + 1);    // sub 1 rows

    // P: per wave 32 rows x 80B = 2560B (first 10240B). Merge aliases:
    // Ob[g] = 32 rows x 76 f32 (9728B) at g*9728; lb 512B at 19456.
    __shared__ __align__(16) char Plds[20480];
    char* lp = Plds + wave * 2560;

    const size_t bh = (size_t)b * H_ + h;
    const short* qb  = qg  + bh * (size_t)T_ * D_;
    const short* kb  = kg  + bh * (size_t)T_ * D_;
    const short* vtb = vtg + bh * (size_t)D_ * T_;
    const float* biasb = biasg + (size_t)b * T_;

    int rw[2];
#pragma unroll
    for (int sub = 0; sub < 2; ++sub) rw[sub] = (sub * 16 + c) * 80;

    // Q fragments (B operand of S^T)
    bf16x8 qf[2][2];
#pragma unroll
    for (int sub = 0; sub < 2; ++sub) {
        int qrow = ((sub == 0) ? ql0 : qh0) + c;
#pragma unroll
        for (int half = 0; half < 2; ++half)
            qf[sub][half] = *(const bf16x8*)(qb + (size_t)qrow * D_ + half * 32 + quad * 8);
    }

    // ones A-fragment (row m=0) for l-row MFMA
    bf16x8 onesf = {0,0,0,0,0,0,0,0};
    if (c == 0) {
        const short one = 0x3F80;
        onesf = (bf16x8){one,one,one,one,one,one,one,one};
    }

    f32x4 o[4][2] = {};     // [dt][sub]  O^T partial
    f32x4 lacc[2] = {};

    const int tmax = 63 - z;
    for (int tt = ws; tt <= tmax; tt += 2) {
        const int s0 = tt * 32;
        const int sbeg = (tt <= z) ? 0 : 1;
        const bool mlow = (tt == z), mhigh = (tt == tmax);

        bf16x8 ka[2][2];
#pragma unroll
        for (int kst = 0; kst < 2; ++kst)
#pragma unroll
            for (int half = 0; half < 2; ++half)
                ka[kst][half] = *(const bf16x8*)(kb + (size_t)(s0 + kst * 16 + c) * D_
                                                 + half * 32 + quad * 8);
        float4 bx4 = *(const float4*)(biasb + s0 + quad * 4);
        float4 by4 = *(const float4*)(biasb + s0 + 16 + quad * 4);
        const float bx[4] = {bx4.x, bx4.y, bx4.z, bx4.w};
        const float by[4] = {by4.x, by4.y, by4.z, by4.w};

#pragma unroll
        for (int sub = 0; sub < 2; ++sub) {
            if (sub < sbeg) continue;
            f32x4 sx = {0,0,0,0}, sy = {0,0,0,0};
            sx = __builtin_amdgcn_mfma_f32_16x16x32_bf16(ka[0][0], qf[sub][0], sx, 0,0,0);
            sx = __builtin_amdgcn_mfma_f32_16x16x32_bf16(ka[0][1], qf[sub][1], sx, 0,0,0);
            sy = __builtin_amdgcn_mfma_f32_16x16x32_bf16(ka[1][0], qf[sub][0], sy, 0,0,0);
            sy = __builtin_amdgcn_mfma_f32_16x16x32_bf16(ka[1][1], qf[sub][1], sy, 0,0,0);

            float px[4], py[4];
#pragma unroll
            for (int i = 0; i < 4; ++i) {
                px[i] = __builtin_amdgcn_exp2f(fmaf(sx[i], 0.18033688f, bx[i]));
                py[i] = __builtin_amdgcn_exp2f(fmaf(sy[i], 0.18033688f, by[i]));
            }
            const bool msk = (sub == 0) ? mlow : mhigh;
            if (msk) {
                const int qq = ((sub == 0) ? 16 * g : 16 * (1 - g)) + c;
#pragma unroll
                for (int i = 0; i < 4; ++i) {
                    if (quad * 4 + i      > qq) px[i] = 0.0f;
                    if (16 + quad * 4 + i > qq) py[i] = 0.0f;
                }
            }
            uint2 wx = {pk2(px[0], px[1]), pk2(px[2], px[3])};
            uint2 wy = {pk2(py[0], py[1]), pk2(py[2], py[3])};
            *(uint2*)(lp + rw[sub] + quad * 8)      = wx;
            *(uint2*)(lp + rw[sub] + 32 + quad * 8) = wy;
        }

        bf16x8 va[4];
#pragma unroll
        for (int dt = 0; dt < 4; ++dt)
            va[dt] = *(const bf16x8*)(vtb + (size_t)(dt * 16 + c) * T_ + s0 + quad * 8);

#pragma unroll
        for (int sub = 0; sub < 2; ++sub) {
            if (sub < sbeg) continue;
            bf16x8 pf = *(const bf16x8*)(lp + rw[sub] + quad * 16);
#pragma unroll
            for (int dt = 0; dt < 4; ++dt)
                o[dt][sub] = __builtin_amdgcn_mfma_f32_16x16x32_bf16(
                    va[dt], pf, o[dt][sub], 0, 0, 0);
            lacc[sub] = __builtin_amdgcn_mfma_f32_16x16x32_bf16(
                onesf, pf, lacc[sub], 0, 0, 0);
        }
    }

    // ---- merge 2 key-split partials per group (linear: static max) ----
    float* lb = (float*)(Plds + 19456);            // [g][ws][32 q]
    if (quad == 0) {
#pragma unroll
        for (int sub = 0; sub < 2; ++sub)
            lb[(g * 2 + ws) * 32 + sub * 16 + c] = lacc[sub][0];
    }
    __syncthreads();                               // P reads done; lb visible later
    float* Ob = (float*)(Plds + g * 9728);         // [32 q][76 f]
    if (ws == 0) {
#pragma unroll
        for (int sub = 0; sub < 2; ++sub)
#pragma unroll
            for (int dt = 0; dt < 4; ++dt)
                *(f32x4*)&Ob[(sub * 16 + c) * 76 + dt * 16 + quad * 4] = o[dt][sub];
    }
    __syncthreads();
    if (ws == 1) {
#pragma unroll
        for (int sub = 0; sub < 2; ++sub)
#pragma unroll
            for (int dt = 0; dt < 4; ++dt) {
                float* p = &Ob[(sub * 16 + c) * 76 + dt * 16 + quad * 4];
                f32x4 t = *(f32x4*)p;
                t += o[dt][sub];
                *(f32x4*)p = t;
            }
    }
    __syncthreads();

    // ---- normalize + store: thread -> (row r of 64, 16 consecutive d) ----
    const int r  = tid >> 2;                       // 0..63
    const int gg = r >> 5, ql = r & 31;
    const int u  = tid & 3;
    const float lsum = lb[gg * 64 + ql] + lb[gg * 64 + 32 + ql];
    const float inv = 1.0f / lsum;
    const int t = (ql < 16) ? (32 * z + 16 * gg + ql)
                            : (T_ - 32 * z - 16 * (gg + 1) + (ql - 16));

    const float* Og = (const float*)(Plds + gg * 9728);
    bf16x8 r0, r1;
#pragma unroll
    for (int j = 0; j < 8; ++j) {
        r0[j] = f2bf(Og[ql * 76 + u * 16 + j] * inv);
        r1[j] = f2bf(Og[ql * 76 + u * 16 + 8 + j] * inv);
    }
    short* ab = attn + ((size_t)b * T_ + t) * E_ + h * D_ + u * 16;
    *(bf16x8*)ab       = r0;
    *(bf16x8*)(ab + 8) = r1;
}

// ---------------------------------------------------------------------------
extern "C" void kernel_launch(void* const* d_in, const int* in_sizes, int n_in,
                              void* d_out, int out_size, void* d_ws, size_t ws_size,
                              hipStream_t stream) {
    const float* x    = (const float*)d_in[0];
    const float* mask = (const float*)d_in[1];
    const float* Wq   = (const float*)d_in[2];
    const float* Wk   = (const float*)d_in[3];
    const float* Wv   = (const float*)d_in[4];
    const float* Wo   = (const float*)d_in[5];
    const float* bo   = (const float*)d_in[6];
    float* out        = (float*)d_out;

    const size_t S = (size_t)M_ * E_;              // 8.4M elems
    char* ws = (char*)d_ws;
    short* xb   = (short*)ws;                      // bf16 x; reused as attn
    short* qb   = (short*)(ws + S * 2);
    short* kb   = (short*)(ws + S * 4);
    short* vtb  = (short*)(ws + S * 6);            // V stored transposed by MODE0
    short* Wt   = (short*)(ws + S * 8);
    short* Wob  = (short*)(ws + S * 8 + (size_t)3 * 1024 * 1024 * 2);
    float* bias = (float*)(ws + S * 8 + (size_t)4 * 1024 * 1024 * 2);
    short* attnb = xb;

    conv_bf16<<<dim3(M_ * E_ / 1024), 256, 0, stream>>>(x, xb);
    conv_bf16<<<dim3(E_ * E_ / 1024), 256, 0, stream>>>(Wo, Wob);
    wtrans<<<dim3(E_ / 64, H_, 3), 256, 0, stream>>>(Wq, Wk, Wv, Wt);
    bias_prep<<<dim3(B_ * T_ / 256), 256, 0, stream>>>(mask, bias);

    mfma_gemm<0><<<dim3(M_ / 128, 3 * E_ / 128), 256, 0, stream>>>(
        xb, Wt, qb, kb, vtb, nullptr, nullptr);

    flash_attn4<<<dim3(H_, B_, T_ / 64), 256, 0, stream>>>(qb, kb, vtb, bias, attnb);

    mfma_gemm<1><<<dim3(M_ / 128, E_ / 128), 256, 0, stream>>>(
        attnb, Wob, nullptr, nullptr, nullptr, out, bo);
}